// Round 16
// baseline (113.851 us; speedup 1.0000x reference)
//
#include <hip/hip_runtime.h>

#define NSEG 8192           // faces per set
#define NPTS (3 * NSEG)     // 24576 unified points [S | T | R]
#define NSUP 96             // 256-point super-tiles (32 per segment)
#define NXB  96             // one block per super-tile row (2 i-tiles/wave)
#define NYG  25             // y-groups: g<24 -> Y=2g,2g+1; g==24 -> Y=48

typedef short bf16x8 __attribute__((ext_vector_type(8)));   // 8 bf16 (4 VGPRs)
typedef float f32x16 __attribute__((ext_vector_type(16)));  // 16 fp32 acc
typedef unsigned short u16;

__device__ __forceinline__ u16 f2bf(float x) {              // RNE f32 -> bf16 bits
    unsigned u = __builtin_bit_cast(unsigned, x);
    return (u16)((u + 0x7FFFu + ((u >> 16) & 1u)) >> 16);
}
__device__ __forceinline__ float bf2f(u16 h) {
    unsigned u = ((unsigned)h) << 16;
    return __builtin_bit_cast(float, u);
}

__device__ __forceinline__ void compute_point(
    int seg, int f,
    const float* __restrict__ sv, const int* __restrict__ si,
    const float* __restrict__ tv, const int* __restrict__ ti,
    const float* __restrict__ rn, const float* __restrict__ rc,
    float& cx, float& cy, float& cz, float& nx, float& ny, float& nz)
{
    if (seg == 2) {
        nx = rn[3*f];   ny = rn[3*f+1]; nz = rn[3*f+2];
        cx = rc[3*f];   cy = rc[3*f+1]; cz = rc[3*f+2];
    } else {
        const float* v  = (seg == 0) ? sv : tv;
        const int*   nd = (seg == 0) ? si : ti;
        int i0 = nd[3*f], i1 = nd[3*f+1], i2 = nd[3*f+2];
        float ax = v[3*i0], ay = v[3*i0+1], az = v[3*i0+2];
        float bx = v[3*i1], by = v[3*i1+1], bz = v[3*i1+2];
        float gx = v[3*i2], gy = v[3*i2+1], gz = v[3*i2+2];
        float ux = ax-bx, uy = ay-by, uz = az-bz;
        float wx = gx-bx, wy = gy-by, wz = gz-bz;
        nx = 0.5f*(uy*wz - uz*wy);
        ny = 0.5f*(uz*wx - ux*wz);
        nz = 0.5f*(ux*wy - uy*wx);
        cx = (ax+bx+gx)*(1.0f/3.0f);
        cy = (ay+by+gy)*(1.0f/3.0f);
        cz = (az+bz+gz)*(1.0f/3.0f);
    }
}

// Feature rows (K=16 bf16), hi/lo split: t = A_t . B_t = 1+|ci-cj|^2 (~1e-3 abs err).
// Interleaved records: A-side point = {at[16], an[16]} (64 B), B-side = {bt[16], bn[16]}.
__global__ void setup_feats(const float* __restrict__ sv, const int* __restrict__ si,
                            const float* __restrict__ tv, const int* __restrict__ ti,
                            const float* __restrict__ rn, const float* __restrict__ rc,
                            u16* __restrict__ ws, float* __restrict__ out) {
    int p = blockIdx.x * 256 + threadIdx.x;
    if (p == 0) out[0] = 0.0f;          // d_out poisoned 0xAA before every launch
    if (p >= NPTS) return;
    int seg = p >> 13, f = p & (NSEG - 1);
    float cx, cy, cz, nx, ny, nz;
    compute_point(seg, f, sv, si, tv, ti, rn, rc, cx, cy, cz, nx, ny, nz);

    const u16 ONE = 0x3F80;
    float s = cx*cx + cy*cy + cz*cz;
    u16 chx = f2bf(cx), chy = f2bf(cy), chz = f2bf(cz);
    u16 clx = f2bf(cx - bf2f(chx)), cly = f2bf(cy - bf2f(chy)), clz = f2bf(cz - bf2f(chz));
    u16 sh  = f2bf(s);
    u16 sl  = f2bf(s - bf2f(sh));
    u16 m2hx = f2bf(-2.0f*bf2f(chx)), m2hy = f2bf(-2.0f*bf2f(chy)), m2hz = f2bf(-2.0f*bf2f(chz));
    u16 m2lx = f2bf(-2.0f*bf2f(clx)), m2ly = f2bf(-2.0f*bf2f(cly)), m2lz = f2bf(-2.0f*bf2f(clz));
    u16 nhx = f2bf(nx), nhy = f2bf(ny), nhz = f2bf(nz);
    u16 nlx = f2bf(nx - bf2f(nhx)), nly = f2bf(ny - bf2f(nhy)), nlz = f2bf(nz - bf2f(nhz));

    u16 at[16] = {chx,chy,chz, clx,cly,clz, chx,chy,chz, sh, sl, ONE, ONE, ONE, 0, 0};
    u16 bt[16] = {m2hx,m2hy,m2hz, m2hx,m2hy,m2hz, m2lx,m2ly,m2lz, ONE, ONE, sh, sl, ONE, 0, 0};
    u16 an[16] = {nhx,nhy,nhz, nlx,nly,nlz, nhx,nhy,nhz, 0,0,0,0,0,0,0};
    u16 bn[16] = {nhx,nhy,nhz, nhx,nhy,nhz, nlx,nly,nlz, 0,0,0,0,0,0,0};

    bf16x8* A8 = (bf16x8*)ws;            // A-record: frags [at0 at1 an0 an1] per point
    bf16x8* B8 = A8 + (size_t)NPTS*4;    // B-record: frags [bt0 bt1 bn0 bn1] per point
    bf16x8 v0, v1, v2, v3;
    #pragma unroll
    for (int k = 0; k < 8; ++k) { v0[k] = (short)at[k]; v1[k] = (short)at[k+8];
                                  v2[k] = (short)an[k]; v3[k] = (short)an[k+8]; }
    A8[(size_t)p*4+0] = v0; A8[(size_t)p*4+1] = v1; A8[(size_t)p*4+2] = v2; A8[(size_t)p*4+3] = v3;
    #pragma unroll
    for (int k = 0; k < 8; ++k) { v0[k] = (short)bt[k]; v1[k] = (short)bt[k+8];
                                  v2[k] = (short)bn[k]; v3[k] = (short)bn[k+8]; }
    B8[(size_t)p*4+0] = v0; B8[(size_t)p*4+1] = v1; B8[(size_t)p*4+2] = v2; B8[(size_t)p*4+3] = v3;
}

// Symmetric-pair kernel. R24 = R23 (session best 52.5 us: LDS staging with
// transposed conflict-free layout, unroll 2) with the MFMA pair moved to
// INLINE ASM with "=&v" (VGPR) destination constraints. WHY: instruction
// accounting doesn't close — source math is ~36 slots/jt (~6 us/SIMD) but
// measured VALU-busy is ~33 us. VGPR_Count=52 can't contain the 32 acc regs
// -> accumulators are AGPR-allocated, so all 32 elements consumed per MFMA
// pair are v_accvgpr_read (~64 extra VALU insts/jt, ~3x the EPI stream).
// gfx950's unified file makes VGPR C/D legal (ISA §10); the asm constraint
// forces it. HAZARD: compiler can't see through asm, so 2x s_nop 7 (16 cyc)
// inside the block puts XDL-write -> VALU-read distance at >=24 cyc (first
// MFMA) / >=30 cyc (second, +7 EPI insts before first cn use) — beyond the
// ~18-waitstate requirement. Padding 32 cyc/jt vs ~128 cyc/jt saved.
// Same hardware op, same Z, same inputs -> bitwise-identical energy.
// Diagnostic signature: VGPR_Count should jump to ~100-112.
// Gates: absmax 0 (!=0 -> hazard, more nops), WRITE_SIZE ~75 B, FETCH ~7 MB.
// Wrapped map over 256-pt super-tiles: (I,J) = (X, (X+Y)%96); mult = 2 except
// Y==0 (diagonal, once) and Y==48 (hit from both ends) -> 96+96+96*47*2 = 96^2. ✓
__launch_bounds__(256, 4)
__global__ void energy_mfma(const u16* __restrict__ ws, float* __restrict__ out) {
    const int tid  = threadIdx.x;
    const int lane = tid & 63, wid = tid >> 6;
    const int half = lane >> 5, r32 = lane & 31;

    const int X  = blockIdx.x;                // 0..95 (super-tile row)
    const int g  = blockIdx.y;                // 0..24
    const int y0  = (g < 24) ? 2*g : 48;
    const int ycnt = (g < 24) ? 2 : 1;
    const int gi = X >> 5;                    // 32 super-tiles per segment

    const bf16x8* A8 = (const bf16x8*)ws;
    const bf16x8* B8 = A8 + (size_t)NPTS*4;

    // two persistent 32-row i-tiles per wave: rows pi and pi+128
    const int pi = X*256 + wid*32 + r32;
    const bf16x8 at0 = A8[pi*4 + half];
    const bf16x8 an0 = A8[pi*4 + 2 + half];
    const bf16x8 at1 = A8[pi*4 + 512 + half];        // +128 points * 4 frags
    const bf16x8 an1 = A8[pi*4 + 514 + half];

    // stage B-supertiles into LDS, TRANSPOSED: [y][plane c][point p]
    __shared__ bf16x8 ldsB[2][4][256];               // 32 KB
    #pragma unroll
    for (int k = 0; k < 2; ++k) {
        if (k < ycnt) {
            int J = X + y0 + k; if (J >= NSUP) J -= NSUP;
            const bf16x8* srcB = B8 + J*1024;
            #pragma unroll
            for (int rep = 0; rep < 4; ++rep) {      // coalesced 16 B/lane reads
                int f = rep*256 + tid;               // linear frag index
                ldsB[k][f & 3][f >> 2] = srcB[f];    // c = f&3, p = f>>2
            }
        }
    }
    __syncthreads();

    f32x16 Z;
    #pragma unroll
    for (int k = 0; k < 16; ++k) Z[k] = 0.0f;

    // MFMA pair with VGPR destinations (no AGPR round-trip). s_nop padding
    // covers the XDL-write -> VALU-read waitstates the compiler can't model.
#define MFMA2(AT, AN, BT, BN, CT, CN)                                         \
    asm("v_mfma_f32_32x32x16_bf16 %0, %2, %3, %6\n\t"                         \
        "v_mfma_f32_32x32x16_bf16 %1, %4, %5, %6\n\t"                         \
        "s_nop 7\n\t"                                                         \
        "s_nop 7"                                                             \
        : "=&v"(CT), "=&v"(CN)                                                \
        : "v"(AT), "v"(BT), "v"(AN), "v"(BN), "v"(Z))

    // batched rcp: one v_rcp per 4 pairs; two independent partial chains
#define EPI(CT, CN, TS0, TS1) do {                                            \
        _Pragma("unroll")                                                     \
        for (int gq = 0; gq < 4; ++gq) {                                      \
            float t0 = CT[4*gq+0], t1 = CT[4*gq+1];                           \
            float t2 = CT[4*gq+2], t3 = CT[4*gq+3];                           \
            float q0 = t0*t0, q1 = t1*t1, q2 = t2*t2, q3 = t3*t3;             \
            float s01 = q0*q1, s23 = q2*q3;                                   \
            float r   = __builtin_amdgcn_rcpf(s01*s23);                       \
            float u   = __builtin_fmaf(CN[4*gq+1], q0, CN[4*gq+0]*q1);        \
            float v   = __builtin_fmaf(CN[4*gq+3], q2, CN[4*gq+2]*q3);        \
            float num = __builtin_fmaf(v, s01, u*s23);                        \
            if (gq & 1) TS1 = __builtin_fmaf(num, r, TS1);                    \
            else        TS0 = __builtin_fmaf(num, r, TS0);                    \
        }                                                                     \
    } while (0)

    float acc = 0.0f;
    #pragma unroll 1
    for (int yy = 0; yy < ycnt; ++yy) {
        const int y = y0 + yy;
        int J = X + y; if (J >= NSUP) J -= NSUP;
        const int jg = J >> 5;
        float base_w;
        if (gi == jg)                 base_w = (gi == 2) ? 2.0f : 1.8f;
        else if (gi == 2 || jg == 2)  base_w = -1.0f;
        else                          base_w = -0.8f;
        const float w = base_w * ((y == 0 || y == 48) ? 1.0f : 2.0f);

        // per-lane LDS base pointers (plane half / 2+half, point r32);
        // each 32-lane half reads 512 consecutive bytes -> conflict-free
        const bf16x8* Bt = &ldsB[yy][half][r32];
        const bf16x8* Bn = &ldsB[yy][2 + half][r32];

        float tsA0 = 0.0f, tsA1 = 0.0f;       // i-tile 0 partials
        float tsB0 = 0.0f, tsB1 = 0.0f;       // i-tile 1 partials
        #pragma unroll 2
        for (int jt = 0; jt < 8; ++jt) {
            bf16x8 bt = Bt[jt*32];            // ds_read_b128, +512 B per jt
            bf16x8 bn = Bn[jt*32];

            f32x16 ct, cn;
            MFMA2(at0, an0, bt, bn, ct, cn);
            EPI(ct, cn, tsA0, tsA1);
            MFMA2(at1, an1, bt, bn, ct, cn);
            EPI(ct, cn, tsB0, tsB1);
        }
        acc = __builtin_fmaf(w, tsA0 + tsA1, acc);
        acc = __builtin_fmaf(w, tsB0 + tsB1, acc);
    }
#undef EPI
#undef MFMA2

    // wave shuffle reduce -> 4 partials -> one atomic per block
    for (int off = 32; off; off >>= 1) acc += __shfl_down(acc, off, 64);
    __shared__ float partial[4];
    if ((tid & 63) == 0) partial[wid] = acc;
    __syncthreads();
    if (tid == 0)
        atomicAdd(out, (partial[0] + partial[1]) + (partial[2] + partial[3]));
}

extern "C" void kernel_launch(void* const* d_in, const int* in_sizes, int n_in,
                              void* d_out, int out_size, void* d_ws, size_t ws_size,
                              hipStream_t stream) {
    const float* sv = (const float*)d_in[0];
    const int*   si = (const int*)d_in[1];
    const float* tv = (const float*)d_in[2];
    const int*   ti = (const int*)d_in[3];
    const float* rn = (const float*)d_in[4];
    const float* rc = (const float*)d_in[5];
    float* out = (float*)d_out;
    u16*   ws  = (u16*)d_ws;                      // 2 x 24576 x 64 B = 3 MB features

    setup_feats<<<NPTS/256, 256, 0, stream>>>(sv, si, tv, ti, rn, rc, ws, out);
    dim3 grid(NXB, NYG);                          // 96 x 25 = 2400 blocks of 256
    energy_mfma<<<grid, 256, 0, stream>>>(ws, out);
}

// Round 17
// 110.581 us; speedup vs baseline: 1.0296x; 1.0296x over previous
//
#include <hip/hip_runtime.h>

#define NSEG 8192           // faces per set
#define NPTS (3 * NSEG)     // 24576 unified points [S | T | R]
#define NSUP 96             // 256-point super-tiles (32 per segment)
#define NXB  96             // one block per super-tile row (2 i-tiles/wave)
#define NYG  25             // y-groups: g<24 -> Y=2g,2g+1; g==24 -> Y=48

typedef short bf16x8 __attribute__((ext_vector_type(8)));   // 8 bf16 (4 VGPRs)
typedef float f32x16 __attribute__((ext_vector_type(16)));  // 16 fp32 acc
typedef unsigned short u16;

__device__ __forceinline__ u16 f2bf(float x) {              // RNE f32 -> bf16 bits
    unsigned u = __builtin_bit_cast(unsigned, x);
    return (u16)((u + 0x7FFFu + ((u >> 16) & 1u)) >> 16);
}
__device__ __forceinline__ float bf2f(u16 h) {
    unsigned u = ((unsigned)h) << 16;
    return __builtin_bit_cast(float, u);
}

__device__ __forceinline__ void compute_point(
    int seg, int f,
    const float* __restrict__ sv, const int* __restrict__ si,
    const float* __restrict__ tv, const int* __restrict__ ti,
    const float* __restrict__ rn, const float* __restrict__ rc,
    float& cx, float& cy, float& cz, float& nx, float& ny, float& nz)
{
    if (seg == 2) {
        nx = rn[3*f];   ny = rn[3*f+1]; nz = rn[3*f+2];
        cx = rc[3*f];   cy = rc[3*f+1]; cz = rc[3*f+2];
    } else {
        const float* v  = (seg == 0) ? sv : tv;
        const int*   nd = (seg == 0) ? si : ti;
        int i0 = nd[3*f], i1 = nd[3*f+1], i2 = nd[3*f+2];
        float ax = v[3*i0], ay = v[3*i0+1], az = v[3*i0+2];
        float bx = v[3*i1], by = v[3*i1+1], bz = v[3*i1+2];
        float gx = v[3*i2], gy = v[3*i2+1], gz = v[3*i2+2];
        float ux = ax-bx, uy = ay-by, uz = az-bz;
        float wx = gx-bx, wy = gy-by, wz = gz-bz;
        nx = 0.5f*(uy*wz - uz*wy);
        ny = 0.5f*(uz*wx - ux*wz);
        nz = 0.5f*(ux*wy - uy*wx);
        cx = (ax+bx+gx)*(1.0f/3.0f);
        cy = (ay+by+gy)*(1.0f/3.0f);
        cz = (az+bz+gz)*(1.0f/3.0f);
    }
}

// Feature rows (K=16 bf16), hi/lo split: t = A_t . B_t = 1+|ci-cj|^2 (~1e-3 abs err).
// Interleaved records: A-side point = {at[16], an[16]} (64 B), B-side = {bt[16], bn[16]}.
__global__ void setup_feats(const float* __restrict__ sv, const int* __restrict__ si,
                            const float* __restrict__ tv, const int* __restrict__ ti,
                            const float* __restrict__ rn, const float* __restrict__ rc,
                            u16* __restrict__ ws, float* __restrict__ out) {
    int p = blockIdx.x * 256 + threadIdx.x;
    if (p == 0) out[0] = 0.0f;          // d_out poisoned 0xAA before every launch
    if (p >= NPTS) return;
    int seg = p >> 13, f = p & (NSEG - 1);
    float cx, cy, cz, nx, ny, nz;
    compute_point(seg, f, sv, si, tv, ti, rn, rc, cx, cy, cz, nx, ny, nz);

    const u16 ONE = 0x3F80;
    float s = cx*cx + cy*cy + cz*cz;
    u16 chx = f2bf(cx), chy = f2bf(cy), chz = f2bf(cz);
    u16 clx = f2bf(cx - bf2f(chx)), cly = f2bf(cy - bf2f(chy)), clz = f2bf(cz - bf2f(chz));
    u16 sh  = f2bf(s);
    u16 sl  = f2bf(s - bf2f(sh));
    u16 m2hx = f2bf(-2.0f*bf2f(chx)), m2hy = f2bf(-2.0f*bf2f(chy)), m2hz = f2bf(-2.0f*bf2f(chz));
    u16 m2lx = f2bf(-2.0f*bf2f(clx)), m2ly = f2bf(-2.0f*bf2f(cly)), m2lz = f2bf(-2.0f*bf2f(clz));
    u16 nhx = f2bf(nx), nhy = f2bf(ny), nhz = f2bf(nz);
    u16 nlx = f2bf(nx - bf2f(nhx)), nly = f2bf(ny - bf2f(nhy)), nlz = f2bf(nz - bf2f(nhz));

    u16 at[16] = {chx,chy,chz, clx,cly,clz, chx,chy,chz, sh, sl, ONE, ONE, ONE, 0, 0};
    u16 bt[16] = {m2hx,m2hy,m2hz, m2hx,m2hy,m2hz, m2lx,m2ly,m2lz, ONE, ONE, sh, sl, ONE, 0, 0};
    u16 an[16] = {nhx,nhy,nhz, nlx,nly,nlz, nhx,nhy,nhz, 0,0,0,0,0,0,0};
    u16 bn[16] = {nhx,nhy,nhz, nhx,nhy,nhz, nlx,nly,nlz, 0,0,0,0,0,0,0};

    bf16x8* A8 = (bf16x8*)ws;            // A-record: frags [at0 at1 an0 an1] per point
    bf16x8* B8 = A8 + (size_t)NPTS*4;    // B-record: frags [bt0 bt1 bn0 bn1] per point
    bf16x8 v0, v1, v2, v3;
    #pragma unroll
    for (int k = 0; k < 8; ++k) { v0[k] = (short)at[k]; v1[k] = (short)at[k+8];
                                  v2[k] = (short)an[k]; v3[k] = (short)an[k+8]; }
    A8[(size_t)p*4+0] = v0; A8[(size_t)p*4+1] = v1; A8[(size_t)p*4+2] = v2; A8[(size_t)p*4+3] = v3;
    #pragma unroll
    for (int k = 0; k < 8; ++k) { v0[k] = (short)bt[k]; v1[k] = (short)bt[k+8];
                                  v2[k] = (short)bn[k]; v3[k] = (short)bn[k+8]; }
    B8[(size_t)p*4+0] = v0; B8[(size_t)p*4+1] = v1; B8[(size_t)p*4+2] = v2; B8[(size_t)p*4+3] = v3;
}

// Symmetric-pair kernel. R25 = R23 byte-for-byte — the session best (52.5 us
// kernel, 111.0 us total), restored after R24's asm-MFMA experiment regressed
// (56.9 us; s_nop padding + lost compiler scheduling > accvgpr savings, and
// the VGPR signature never appeared — theory unconfirmed).
// Structure: 32x32x16 MFMA, 2 i-tiles/wave, LDS-staged B with TRANSPOSED
// [y][plane c][point p] layout (read conflict-free: each 32-lane half reads
// 512 consecutive bytes; residual 1.8M conflicts are the one-time staging
// write), #pragma unroll 2 jt loop (the only non-spilling schedule — 4
// deeper-pipelining attempts all hit the unified-file spill cliff), NYG=25.
// Floor evidence: VALU-busy ~33 us invariant across 10 structural variants;
// 3 load paths within noise; occupancy/launch-bounds/geometry levers null.
// Accumulation order within (X,y,jt,gq,i-tile) fixed -> bitwise-stable energy.
// Wrapped map over 256-pt super-tiles: (I,J) = (X, (X+Y)%96); mult = 2 except
// Y==0 (diagonal, once) and Y==48 (hit from both ends) -> 96+96+96*47*2 = 96^2. ✓
__launch_bounds__(256, 4)
__global__ void energy_mfma(const u16* __restrict__ ws, float* __restrict__ out) {
    const int tid  = threadIdx.x;
    const int lane = tid & 63, wid = tid >> 6;
    const int half = lane >> 5, r32 = lane & 31;

    const int X  = blockIdx.x;                // 0..95 (super-tile row)
    const int g  = blockIdx.y;                // 0..24
    const int y0  = (g < 24) ? 2*g : 48;
    const int ycnt = (g < 24) ? 2 : 1;
    const int gi = X >> 5;                    // 32 super-tiles per segment

    const bf16x8* A8 = (const bf16x8*)ws;
    const bf16x8* B8 = A8 + (size_t)NPTS*4;

    // two persistent 32-row i-tiles per wave: rows pi and pi+128
    const int pi = X*256 + wid*32 + r32;
    const bf16x8 at0 = A8[pi*4 + half];
    const bf16x8 an0 = A8[pi*4 + 2 + half];
    const bf16x8 at1 = A8[pi*4 + 512 + half];        // +128 points * 4 frags
    const bf16x8 an1 = A8[pi*4 + 514 + half];

    // stage B-supertiles into LDS, TRANSPOSED: [y][plane c][point p]
    __shared__ bf16x8 ldsB[2][4][256];               // 32 KB
    #pragma unroll
    for (int k = 0; k < 2; ++k) {
        if (k < ycnt) {
            int J = X + y0 + k; if (J >= NSUP) J -= NSUP;
            const bf16x8* srcB = B8 + J*1024;
            #pragma unroll
            for (int rep = 0; rep < 4; ++rep) {      // coalesced 16 B/lane reads
                int f = rep*256 + tid;               // linear frag index
                ldsB[k][f & 3][f >> 2] = srcB[f];    // c = f&3, p = f>>2
            }
        }
    }
    __syncthreads();

    f32x16 Z;
    #pragma unroll
    for (int k = 0; k < 16; ++k) Z[k] = 0.0f;

    // batched rcp: one v_rcp per 4 pairs; two independent partial chains
#define EPI(CT, CN, TS0, TS1) do {                                            \
        _Pragma("unroll")                                                     \
        for (int gq = 0; gq < 4; ++gq) {                                      \
            float t0 = CT[4*gq+0], t1 = CT[4*gq+1];                           \
            float t2 = CT[4*gq+2], t3 = CT[4*gq+3];                           \
            float q0 = t0*t0, q1 = t1*t1, q2 = t2*t2, q3 = t3*t3;             \
            float s01 = q0*q1, s23 = q2*q3;                                   \
            float r   = __builtin_amdgcn_rcpf(s01*s23);                       \
            float u   = __builtin_fmaf(CN[4*gq+1], q0, CN[4*gq+0]*q1);        \
            float v   = __builtin_fmaf(CN[4*gq+3], q2, CN[4*gq+2]*q3);        \
            float num = __builtin_fmaf(v, s01, u*s23);                        \
            if (gq & 1) TS1 = __builtin_fmaf(num, r, TS1);                    \
            else        TS0 = __builtin_fmaf(num, r, TS0);                    \
        }                                                                     \
    } while (0)

    float acc = 0.0f;
    #pragma unroll 1
    for (int yy = 0; yy < ycnt; ++yy) {
        const int y = y0 + yy;
        int J = X + y; if (J >= NSUP) J -= NSUP;
        const int jg = J >> 5;
        float base_w;
        if (gi == jg)                 base_w = (gi == 2) ? 2.0f : 1.8f;
        else if (gi == 2 || jg == 2)  base_w = -1.0f;
        else                          base_w = -0.8f;
        const float w = base_w * ((y == 0 || y == 48) ? 1.0f : 2.0f);

        // per-lane LDS base pointers (plane half / 2+half, point r32);
        // each 32-lane half reads 512 consecutive bytes -> conflict-free
        const bf16x8* Bt = &ldsB[yy][half][r32];
        const bf16x8* Bn = &ldsB[yy][2 + half][r32];

        float tsA0 = 0.0f, tsA1 = 0.0f;       // i-tile 0 partials
        float tsB0 = 0.0f, tsB1 = 0.0f;       // i-tile 1 partials
        #pragma unroll 2
        for (int jt = 0; jt < 8; ++jt) {
            bf16x8 bt = Bt[jt*32];            // ds_read_b128, +512 B per jt
            bf16x8 bn = Bn[jt*32];

            f32x16 ct, cn;
            ct = __builtin_amdgcn_mfma_f32_32x32x16_bf16(at0, bt, Z, 0, 0, 0);
            cn = __builtin_amdgcn_mfma_f32_32x32x16_bf16(an0, bn, Z, 0, 0, 0);
            EPI(ct, cn, tsA0, tsA1);
            ct = __builtin_amdgcn_mfma_f32_32x32x16_bf16(at1, bt, Z, 0, 0, 0);
            cn = __builtin_amdgcn_mfma_f32_32x32x16_bf16(an1, bn, Z, 0, 0, 0);
            EPI(ct, cn, tsB0, tsB1);
        }
        acc = __builtin_fmaf(w, tsA0 + tsA1, acc);
        acc = __builtin_fmaf(w, tsB0 + tsB1, acc);
    }
#undef EPI

    // wave shuffle reduce -> 4 partials -> one atomic per block
    for (int off = 32; off; off >>= 1) acc += __shfl_down(acc, off, 64);
    __shared__ float partial[4];
    if ((tid & 63) == 0) partial[wid] = acc;
    __syncthreads();
    if (tid == 0)
        atomicAdd(out, (partial[0] + partial[1]) + (partial[2] + partial[3]));
}

extern "C" void kernel_launch(void* const* d_in, const int* in_sizes, int n_in,
                              void* d_out, int out_size, void* d_ws, size_t ws_size,
                              hipStream_t stream) {
    const float* sv = (const float*)d_in[0];
    const int*   si = (const int*)d_in[1];
    const float* tv = (const float*)d_in[2];
    const int*   ti = (const int*)d_in[3];
    const float* rn = (const float*)d_in[4];
    const float* rc = (const float*)d_in[5];
    float* out = (float*)d_out;
    u16*   ws  = (u16*)d_ws;                      // 2 x 24576 x 64 B = 3 MB features

    setup_feats<<<NPTS/256, 256, 0, stream>>>(sv, si, tv, ti, rn, rc, ws, out);
    dim3 grid(NXB, NYG);                          // 96 x 25 = 2400 blocks of 256
    energy_mfma<<<grid, 256, 0, stream>>>(ws, out);
}